// Round 9
// baseline (57.212 us; speedup 1.0000x reference)
//
#include <hip/hip_runtime.h>
#include <stdint.h>

// KL pairwise: out[n,m] = ent[n] + sum_d a[n,d]*(-log b[m,d])
// N = M = 8192, D = 64, fp32 in/out.
// Round 9: R7 (champion, 50.46us) + bijective XCD-aware block swizzle.
// Each XCD gets a contiguous 1024-block chunk = a contiguous 32 MB row-slab
// of the output -> per-XCD-L2 write-back stream becomes near-sequential.

typedef __attribute__((ext_vector_type(8))) __bf16 bfx8;
typedef __attribute__((ext_vector_type(8))) unsigned short usx8;
typedef __attribute__((ext_vector_type(4))) float fx4;

#define AS1 __attribute__((address_space(1)))
#define AS3 __attribute__((address_space(3)))

__device__ __forceinline__ unsigned short f2bf(float x) {
    // round-to-nearest-even fp32 -> bf16 (finite inputs)
    unsigned int u = __float_as_uint(x);
    u += 0x7FFFu + ((u >> 16) & 1u);
    return (unsigned short)(u >> 16);
}

// blocks [0, blocksA): A rows -> ent + bf16; blocks [blocksA, ...): B rows -> -log -> bf16
__global__ __launch_bounds__(256)
void prep_kernel(const float* __restrict__ A, const float* __restrict__ B,
                 unsigned short* __restrict__ a16, unsigned short* __restrict__ lb16,
                 float* __restrict__ ent, int blocksA) {
    const int t   = threadIdx.x;
    const int rin = t >> 3;          // row within 32-row group (8 lanes per row)
    const int c8  = (t & 7) * 8;     // col start (8 floats per lane)
    if ((int)blockIdx.x < blocksA) {
        int row = blockIdx.x * 32 + rin;
        const float4* p = (const float4*)(A + (size_t)row * 64 + c8);
        float4 f0 = p[0], f1 = p[1];
        float part = f0.x*__logf(f0.x) + f0.y*__logf(f0.y) +
                     f0.z*__logf(f0.z) + f0.w*__logf(f0.w) +
                     f1.x*__logf(f1.x) + f1.y*__logf(f1.y) +
                     f1.z*__logf(f1.z) + f1.w*__logf(f1.w);
        part += __shfl_xor(part, 1);
        part += __shfl_xor(part, 2);
        part += __shfl_xor(part, 4);
        if ((t & 7) == 0) ent[row] = part;
        usx8 v;
        v[0]=f2bf(f0.x); v[1]=f2bf(f0.y); v[2]=f2bf(f0.z); v[3]=f2bf(f0.w);
        v[4]=f2bf(f1.x); v[5]=f2bf(f1.y); v[6]=f2bf(f1.z); v[7]=f2bf(f1.w);
        *(usx8*)&a16[(size_t)row * 64 + c8] = v;
    } else {
        int row = ((int)blockIdx.x - blocksA) * 32 + rin;
        const float4* p = (const float4*)(B + (size_t)row * 64 + c8);
        float4 f0 = p[0], f1 = p[1];
        usx8 v;
        v[0]=f2bf(-__logf(f0.x)); v[1]=f2bf(-__logf(f0.y));
        v[2]=f2bf(-__logf(f0.z)); v[3]=f2bf(-__logf(f0.w));
        v[4]=f2bf(-__logf(f1.x)); v[5]=f2bf(-__logf(f1.y));
        v[6]=f2bf(-__logf(f1.z)); v[7]=f2bf(-__logf(f1.w));
        *(usx8*)&lb16[(size_t)row * 64 + c8] = v;
    }
}

// Block tile: 128 rows x 64 cols. 4 waves: wr=(wid>>1)*64, wc=(wid&1)*32.
// Grid: flat 8192 blocks; XCD-swizzled (wg&7)*1024 + (wg>>3) -> each XCD
// owns a contiguous 1024-block chunk (8 full brow rows = 32 MB output slab).
__global__ __launch_bounds__(256, 4)
void gemm_kernel(const unsigned short* __restrict__ a16,
                 const unsigned short* __restrict__ lb16,
                 const float* __restrict__ ent,
                 float* __restrict__ out, int Mtot) {
    // LDS content-swizzled: LDS chunk (row,c) holds global chunk (row, c^(row&7));
    // gload_lds dest is linear, swizzle applied to the SOURCE address.
    __shared__ unsigned short sa[128 * 64];   // 16 KB
    __shared__ unsigned short sb[64 * 64];    //  8 KB

    const int t = threadIdx.x, lane = t & 63, wid = t >> 6;

    const int wg   = blockIdx.x;
    const int swz  = (wg & 7) * 1024 + (wg >> 3);   // bijective: 8192 % 8 == 0
    const int bcol = swz & 127;                      // 128 col-tiles
    const int brow = swz >> 7;                       // 64 row-tiles

    const unsigned short* gA = a16  + (size_t)brow * (128 * 64);
    const unsigned short* gB = lb16 + (size_t)bcol * (64 * 64);

    // stage A: 1024 chunks = 4 instrs/thread; B: 512 chunks = 2 instrs/thread
#pragma unroll
    for (int it = 0; it < 4; ++it) {
        int d   = it * 256 + wid * 64 + lane;
        int row = d >> 3, c = d & 7;
        int sc  = row * 8 + (c ^ (row & 7));
        __builtin_amdgcn_global_load_lds(
            (const AS1 unsigned int*)(gA + sc * 8),
            (AS3 unsigned int*)&sa[(it * 256 + wid * 64) * 8], 16, 0, 0);
    }
#pragma unroll
    for (int it = 0; it < 2; ++it) {
        int d   = it * 256 + wid * 64 + lane;
        int row = d >> 3, c = d & 7;
        int sc  = row * 8 + (c ^ (row & 7));
        __builtin_amdgcn_global_load_lds(
            (const AS1 unsigned int*)(gB + sc * 8),
            (AS3 unsigned int*)&sb[(it * 256 + wid * 64) * 8], 16, 0, 0);
    }

    const int l15 = lane & 15, lk = lane >> 4;
    const int wr = (wid >> 1) * 64;     // wave row offset (0 or 64)
    const int wc = (wid & 1) * 32;      // wave col offset (0 or 32)

    // ent for this lane's 4 row fragments (L2-hit, overlaps DMA)
    float e[4];
#pragma unroll
    for (int i = 0; i < 4; ++i) e[i] = ent[brow * 128 + wr + i * 16 + l15];

    __syncthreads();   // drains the DMA (vmcnt 0) + barrier

    // Swapped-operand MFMA: A-op = -log(b) rows -> D-col regs index out-cols;
    // B-op = a rows -> out-row = lane&15 (+i*16). ent preloaded as C.
    fx4 acc[2][4];   // [j = col frag][i = row frag]
#pragma unroll
    for (int j = 0; j < 2; ++j)
#pragma unroll
        for (int i = 0; i < 4; ++i) {
            acc[j][i][0] = e[i]; acc[j][i][1] = e[i];
            acc[j][i][2] = e[i]; acc[j][i][3] = e[i];
        }

#pragma unroll
    for (int ks = 0; ks < 2; ++ks) {
        const int c = ks * 4 + lk;
        bfx8 af[4], bg[2];
#pragma unroll
        for (int i = 0; i < 4; ++i) {
            int ra = wr + i * 16 + l15;
            af[i] = *(const bfx8*)&sa[(ra * 8 + (c ^ (ra & 7))) * 8];
        }
#pragma unroll
        for (int j = 0; j < 2; ++j) {
            int rb = wc + j * 16 + l15;
            bg[j] = *(const bfx8*)&sb[(rb * 8 + (c ^ (rb & 7))) * 8];
        }
#pragma unroll
        for (int j = 0; j < 2; ++j)
#pragma unroll
            for (int i = 0; i < 4; ++i)
                acc[j][i] = __builtin_amdgcn_mfma_f32_16x16x32_bf16(
                    bg[j], af[i], acc[j][i], 0, 0, 0);
    }

    // Stores: per row each wave covers 128 contiguous bytes.
#pragma unroll
    for (int i = 0; i < 4; ++i) {
        size_t row = (size_t)brow * 128 + wr + i * 16 + l15;
        float* p = out + row * (size_t)Mtot + (size_t)bcol * 64 + wc + lk * 4;
#pragma unroll
        for (int j = 0; j < 2; ++j)
            *(fx4*)(p + j * 16) = acc[j][i];
    }
}

extern "C" void kernel_launch(void* const* d_in, const int* in_sizes, int n_in,
                              void* d_out, int out_size, void* d_ws, size_t ws_size,
                              hipStream_t stream) {
    const float* a = (const float*)d_in[0];
    const float* b = (const float*)d_in[1];
    float* out = (float*)d_out;

    const int D = 64;
    const int N = in_sizes[0] / D;   // 8192
    const int M = in_sizes[1] / D;   // 8192

    // ws layout: a16 (N*64 bf16 = 1MB) | lb16 (M*64 bf16 = 1MB) | ent (N fp32 = 32KB)
    unsigned short* a16  = (unsigned short*)d_ws;
    unsigned short* lb16 = (unsigned short*)((char*)d_ws + (size_t)N * 64 * 2);
    float* ent           = (float*)((char*)d_ws + (size_t)(N + M) * 64 * 2);

    const int blocksA = N / 32, blocksB = M / 32;
    hipLaunchKernelGGL(prep_kernel, dim3(blocksA + blocksB), dim3(256), 0, stream,
                       a, b, a16, lb16, ent, blocksA);
    hipLaunchKernelGGL(gemm_kernel, dim3((M / 64) * (N / 128)), dim3(256), 0, stream,
                       a16, lb16, ent, out, M);
}

// Round 10
// 50.382 us; speedup vs baseline: 1.1356x; 1.1356x over previous
//
#include <hip/hip_runtime.h>
#include <stdint.h>

// KL pairwise: out[n,m] = ent[n] + sum_d a[n,d]*(-log b[m,d])
// N = M = 8192, D = 64, fp32 in/out.
// Round 10: R7 (champion) with __launch_bounds__(256,6): VGPR cap 85 ->
// 6 blocks/CU (LDS 24KB allows it) for deeper cross-generation overlap of
// the block front-end under the store stream. Natural 2D grid (bcol fast)
// kept — R9 showed dispatch-order adjacency is the write-locality that matters.

typedef __attribute__((ext_vector_type(8))) __bf16 bfx8;
typedef __attribute__((ext_vector_type(8))) unsigned short usx8;
typedef __attribute__((ext_vector_type(4))) float fx4;

#define AS1 __attribute__((address_space(1)))
#define AS3 __attribute__((address_space(3)))

__device__ __forceinline__ unsigned short f2bf(float x) {
    // round-to-nearest-even fp32 -> bf16 (finite inputs)
    unsigned int u = __float_as_uint(x);
    u += 0x7FFFu + ((u >> 16) & 1u);
    return (unsigned short)(u >> 16);
}

// blocks [0, blocksA): A rows -> ent + bf16; blocks [blocksA, ...): B rows -> -log -> bf16
__global__ __launch_bounds__(256)
void prep_kernel(const float* __restrict__ A, const float* __restrict__ B,
                 unsigned short* __restrict__ a16, unsigned short* __restrict__ lb16,
                 float* __restrict__ ent, int blocksA) {
    const int t   = threadIdx.x;
    const int rin = t >> 3;          // row within 32-row group (8 lanes per row)
    const int c8  = (t & 7) * 8;     // col start (8 floats per lane)
    if ((int)blockIdx.x < blocksA) {
        int row = blockIdx.x * 32 + rin;
        const float4* p = (const float4*)(A + (size_t)row * 64 + c8);
        float4 f0 = p[0], f1 = p[1];
        float part = f0.x*__logf(f0.x) + f0.y*__logf(f0.y) +
                     f0.z*__logf(f0.z) + f0.w*__logf(f0.w) +
                     f1.x*__logf(f1.x) + f1.y*__logf(f1.y) +
                     f1.z*__logf(f1.z) + f1.w*__logf(f1.w);
        part += __shfl_xor(part, 1);
        part += __shfl_xor(part, 2);
        part += __shfl_xor(part, 4);
        if ((t & 7) == 0) ent[row] = part;
        usx8 v;
        v[0]=f2bf(f0.x); v[1]=f2bf(f0.y); v[2]=f2bf(f0.z); v[3]=f2bf(f0.w);
        v[4]=f2bf(f1.x); v[5]=f2bf(f1.y); v[6]=f2bf(f1.z); v[7]=f2bf(f1.w);
        *(usx8*)&a16[(size_t)row * 64 + c8] = v;
    } else {
        int row = ((int)blockIdx.x - blocksA) * 32 + rin;
        const float4* p = (const float4*)(B + (size_t)row * 64 + c8);
        float4 f0 = p[0], f1 = p[1];
        usx8 v;
        v[0]=f2bf(-__logf(f0.x)); v[1]=f2bf(-__logf(f0.y));
        v[2]=f2bf(-__logf(f0.z)); v[3]=f2bf(-__logf(f0.w));
        v[4]=f2bf(-__logf(f1.x)); v[5]=f2bf(-__logf(f1.y));
        v[6]=f2bf(-__logf(f1.z)); v[7]=f2bf(-__logf(f1.w));
        *(usx8*)&lb16[(size_t)row * 64 + c8] = v;
    }
}

// Block tile: 128 rows (A/out rows) x 64 cols (B rows / out cols).
// 4 waves: wr = (wid>>1)*64, wc = (wid&1)*32; wave tile 64x32.
__global__ __launch_bounds__(256, 6)
void gemm_kernel(const unsigned short* __restrict__ a16,
                 const unsigned short* __restrict__ lb16,
                 const float* __restrict__ ent,
                 float* __restrict__ out, int Mtot) {
    // LDS content-swizzled: LDS chunk (row,c) holds global chunk (row, c^(row&7));
    // gload_lds dest is linear, swizzle applied to the SOURCE address.
    __shared__ unsigned short sa[128 * 64];   // 16 KB
    __shared__ unsigned short sb[64 * 64];    //  8 KB

    const int t = threadIdx.x, lane = t & 63, wid = t >> 6;
    const int brow = blockIdx.y, bcol = blockIdx.x;

    const unsigned short* gA = a16  + (size_t)brow * (128 * 64);
    const unsigned short* gB = lb16 + (size_t)bcol * (64 * 64);

    // stage A: 1024 chunks = 4 instrs/thread; B: 512 chunks = 2 instrs/thread
#pragma unroll
    for (int it = 0; it < 4; ++it) {
        int d   = it * 256 + wid * 64 + lane;
        int row = d >> 3, c = d & 7;
        int sc  = row * 8 + (c ^ (row & 7));
        __builtin_amdgcn_global_load_lds(
            (const AS1 unsigned int*)(gA + sc * 8),
            (AS3 unsigned int*)&sa[(it * 256 + wid * 64) * 8], 16, 0, 0);
    }
#pragma unroll
    for (int it = 0; it < 2; ++it) {
        int d   = it * 256 + wid * 64 + lane;
        int row = d >> 3, c = d & 7;
        int sc  = row * 8 + (c ^ (row & 7));
        __builtin_amdgcn_global_load_lds(
            (const AS1 unsigned int*)(gB + sc * 8),
            (AS3 unsigned int*)&sb[(it * 256 + wid * 64) * 8], 16, 0, 0);
    }

    const int l15 = lane & 15, lk = lane >> 4;
    const int wr = (wid >> 1) * 64;     // wave row offset (0 or 64)
    const int wc = (wid & 1) * 32;      // wave col offset (0 or 32)

    // ent for this lane's 4 row fragments (L2-hit, overlaps DMA)
    float e[4];
#pragma unroll
    for (int i = 0; i < 4; ++i) e[i] = ent[brow * 128 + wr + i * 16 + l15];

    __syncthreads();   // drains the DMA (vmcnt 0) + barrier

    // Swapped-operand MFMA: A-op = -log(b) rows -> D-col regs index out-cols;
    // B-op = a rows -> out-row = lane&15 (+i*16). ent preloaded as C.
    fx4 acc[2][4];   // [j = col frag][i = row frag]
#pragma unroll
    for (int j = 0; j < 2; ++j)
#pragma unroll
        for (int i = 0; i < 4; ++i) {
            acc[j][i][0] = e[i]; acc[j][i][1] = e[i];
            acc[j][i][2] = e[i]; acc[j][i][3] = e[i];
        }

#pragma unroll
    for (int ks = 0; ks < 2; ++ks) {
        const int c = ks * 4 + lk;
        bfx8 af[4], bg[2];
#pragma unroll
        for (int i = 0; i < 4; ++i) {
            int ra = wr + i * 16 + l15;
            af[i] = *(const bfx8*)&sa[(ra * 8 + (c ^ (ra & 7))) * 8];
        }
#pragma unroll
        for (int j = 0; j < 2; ++j) {
            int rb = wc + j * 16 + l15;
            bg[j] = *(const bfx8*)&sb[(rb * 8 + (c ^ (rb & 7))) * 8];
        }
#pragma unroll
        for (int j = 0; j < 2; ++j)
#pragma unroll
            for (int i = 0; i < 4; ++i)
                acc[j][i] = __builtin_amdgcn_mfma_f32_16x16x32_bf16(
                    bg[j], af[i], acc[j][i], 0, 0, 0);
    }

    // Stores: per row each wave covers 128 contiguous bytes.
#pragma unroll
    for (int i = 0; i < 4; ++i) {
        size_t row = (size_t)brow * 128 + wr + i * 16 + l15;
        float* p = out + row * (size_t)Mtot + (size_t)bcol * 64 + wc + lk * 4;
#pragma unroll
        for (int j = 0; j < 2; ++j)
            *(fx4*)(p + j * 16) = acc[j][i];
    }
}

extern "C" void kernel_launch(void* const* d_in, const int* in_sizes, int n_in,
                              void* d_out, int out_size, void* d_ws, size_t ws_size,
                              hipStream_t stream) {
    const float* a = (const float*)d_in[0];
    const float* b = (const float*)d_in[1];
    float* out = (float*)d_out;

    const int D = 64;
    const int N = in_sizes[0] / D;   // 8192
    const int M = in_sizes[1] / D;   // 8192

    // ws layout: a16 (N*64 bf16 = 1MB) | lb16 (M*64 bf16 = 1MB) | ent (N fp32 = 32KB)
    unsigned short* a16  = (unsigned short*)d_ws;
    unsigned short* lb16 = (unsigned short*)((char*)d_ws + (size_t)N * 64 * 2);
    float* ent           = (float*)((char*)d_ws + (size_t)(N + M) * 64 * 2);

    const int blocksA = N / 32, blocksB = M / 32;
    hipLaunchKernelGGL(prep_kernel, dim3(blocksA + blocksB), dim3(256), 0, stream,
                       a, b, a16, lb16, ent, blocksA);
    hipLaunchKernelGGL(gemm_kernel, dim3(M / 64, N / 128), dim3(256), 0, stream,
                       a16, lb16, ent, out, M);
}